// Round 2
// baseline (714.679 us; speedup 1.0000x reference)
//
#include <hip/hip_runtime.h>

#define N_NODES 100000
#define N_EDGES 3200000

constexpr float DSIGMA_DT  = -0.0001f;
constexpr float PHI_THRESH = 0.3f;
constexpr float EPS        = 1e-8f;

// Packed 2xf32 atomic add (one 8B transaction instead of two 4B ones).
typedef float v2f __attribute__((ext_vector_type(2)));
#if __has_builtin(__builtin_amdgcn_global_atomic_fadd_v2f32)
typedef __attribute__((address_space(1))) v2f gv2f;
__device__ __forceinline__ void pk_atomic_add(float* addr, float a, float b) {
    v2f v; v.x = a; v.y = b;
    __builtin_amdgcn_global_atomic_fadd_v2f32((gv2f*)(unsigned long long)addr, v);
}
#else
__device__ __forceinline__ void pk_atomic_add(float* addr, float a, float b) {
    atomicAdd(addr, a);
    atomicAdd(addr + 1, b);
}
#endif

// Extract T = x[:,3] into a compact array for cache-dense gathers.
__global__ void extract_T_kernel(const float* __restrict__ x,
                                 float* __restrict__ Tc) {
    int i = blockIdx.x * blockDim.x + threadIdx.x;
    if (i < N_NODES) Tc[i] = x[i * 9 + 3];
}

// Two edges per thread: gather endpoints, compute contribution,
// scatter-add into per-node float4 {num.x, num.y, num.z, cnt}
// with two packed-f32 atomics (same 16B region -> same 32B sector).
__global__ void edge_scatter_kernel(const int2* __restrict__ ei2,
                                    const float* __restrict__ Tc,
                                    const float* __restrict__ pos,
                                    float4* __restrict__ accum) {
    int t = blockIdx.x * blockDim.x + threadIdx.x;
    if (t >= N_EDGES / 2) return;
    int2 s2 = ei2[t];                  // two src indices
    int2 d2 = ei2[N_EDGES / 2 + t];    // two dst indices

#pragma unroll
    for (int k = 0; k < 2; ++k) {
        int s = k ? s2.y : s2.x;
        int d = k ? d2.y : d2.x;

        float dT = Tc[s] - Tc[d];
        float px = pos[3 * s]     - pos[3 * d];
        float py = pos[3 * s + 1] - pos[3 * d + 1];
        float pz = pos[3 * s + 2] - pos[3 * d + 2];
        float dist2 = px * px + py * py + pz * pz + EPS;
        float w = dT / dist2;

        float* a = (float*)&accum[d];
        pk_atomic_add(a,     w * px, w * py);
        pk_atomic_add(a + 2, w * pz, 1.0f);
    }
}

// One thread per node: out = mask * DSIGMA_DT * num / max(cnt,1)
// Fully overwrites d_out, so d_out needs no memset.
__global__ void finalize_kernel(const float* __restrict__ x,
                                const float4* __restrict__ accum,
                                float* __restrict__ out) {
    int i = blockIdx.x * blockDim.x + threadIdx.x;
    if (i >= N_NODES) return;
    float phi = x[i * 9 + 8];
    float4 a = accum[i];
    float c = a.w > 1.0f ? a.w : 1.0f;
    float m = (fabsf(phi) < PHI_THRESH) ? (DSIGMA_DT / c) : 0.0f;
    out[3 * i]     = m * a.x;
    out[3 * i + 1] = m * a.y;
    out[3 * i + 2] = m * a.z;
}

extern "C" void kernel_launch(void* const* d_in, const int* in_sizes, int n_in,
                              void* d_out, int out_size, void* d_ws, size_t ws_size,
                              hipStream_t stream) {
    const float* x   = (const float*)d_in[0];
    const float* pos = (const float*)d_in[1];
    const int*   ei  = (const int*)d_in[2];
    float* out = (float*)d_out;

    // ws layout: [Tc: N_NODES floats][accum: N_NODES float4] (offset 400000 is 16B-aligned)
    float*  Tc    = (float*)d_ws;
    float4* accum = (float4*)((char*)d_ws + (size_t)N_NODES * sizeof(float));

    hipMemsetAsync(accum, 0, (size_t)N_NODES * sizeof(float4), stream);

    const int B = 256;
    extract_T_kernel<<<(N_NODES + B - 1) / B, B, 0, stream>>>(x, Tc);
    edge_scatter_kernel<<<(N_EDGES / 2 + B - 1) / B, B, 0, stream>>>(
        (const int2*)ei, Tc, pos, accum);
    finalize_kernel<<<(N_NODES + B - 1) / B, B, 0, stream>>>(x, accum, out);
}

// Round 3
// 376.961 us; speedup vs baseline: 1.8959x; 1.8959x over previous
//
#include <hip/hip_runtime.h>

#define N_NODES 100000
#define N_EDGES 3200000

#define S_LOG2 12
#define S (1 << S_LOG2)                 // 4096 nodes per partition
#define NPART ((N_NODES + S - 1) / S)   // 25 partitions
#define CHUNKS 16
#define VEC_PER_CHUNK (N_EDGES / 4 / CHUNKS)  // 50000 int4-edges per chunk

constexpr float DSIGMA_DT  = -0.0001f;
constexpr float PHI_THRESH = 0.3f;
constexpr float EPS        = 1e-8f;

// Extract T = x[:,3] into a compact array for cache-dense gathers.
__global__ void extract_T_kernel(const float* __restrict__ x,
                                 float* __restrict__ Tc) {
    int i = blockIdx.x * blockDim.x + threadIdx.x;
    if (i < N_NODES) Tc[i] = x[i * 9 + 3];
}

__device__ __forceinline__ void edge_accum(int s, int d, unsigned r,
                                           const float* __restrict__ Tc,
                                           const float* __restrict__ pos,
                                           float (*lacc)[4]) {
    float dT = Tc[s] - Tc[d];
    float px = pos[3 * s]     - pos[3 * d];
    float py = pos[3 * s + 1] - pos[3 * d + 1];
    float pz = pos[3 * s + 2] - pos[3 * d + 2];
    float dist2 = px * px + py * py + pz * pz + EPS;
    float w = dT / dist2;
    atomicAdd(&lacc[r][0], w * px);
    atomicAdd(&lacc[r][1], w * py);
    atomicAdd(&lacc[r][2], w * pz);
    atomicAdd(&lacc[r][3], 1.0f);
}

// Block (c, p): scan edge chunk c, accumulate contributions for node
// partition p in LDS, flush partials with plain coalesced stores.
__global__ __launch_bounds__(256) void mp_scatter_kernel(
        const int4* __restrict__ ei4,
        const float* __restrict__ Tc,
        const float* __restrict__ pos,
        float4* __restrict__ partials) {
    __shared__ float lacc[S][4];   // 64 KB
    const int c  = blockIdx.x;
    const int p  = blockIdx.y;
    const int lo = p << S_LOG2;

    for (int i = threadIdx.x; i < S * 4; i += 256) ((float*)lacc)[i] = 0.0f;
    __syncthreads();

    const int4* __restrict__ src4 = ei4;
    const int4* __restrict__ dst4 = ei4 + (N_EDGES / 4);
    const int vend = (c + 1) * VEC_PER_CHUNK;
    for (int v = c * VEC_PER_CHUNK + threadIdx.x; v < vend; v += 256) {
        int4 d = dst4[v];
        unsigned r0 = (unsigned)(d.x - lo);
        unsigned r1 = (unsigned)(d.y - lo);
        unsigned r2 = (unsigned)(d.z - lo);
        unsigned r3 = (unsigned)(d.w - lo);
        if ((r0 < S) | (r1 < S) | (r2 < S) | (r3 < S)) {
            int4 s = src4[v];
            if (r0 < S) edge_accum(s.x, d.x, r0, Tc, pos, lacc);
            if (r1 < S) edge_accum(s.y, d.y, r1, Tc, pos, lacc);
            if (r2 < S) edge_accum(s.z, d.z, r2, Tc, pos, lacc);
            if (r3 < S) edge_accum(s.w, d.w, r3, Tc, pos, lacc);
        }
    }
    __syncthreads();

    float4* __restrict__ outp = partials + ((size_t)(p * CHUNKS + c) << S_LOG2);
    for (int i = threadIdx.x; i < S; i += 256) {
        outp[i] = make_float4(lacc[i][0], lacc[i][1], lacc[i][2], lacc[i][3]);
    }
}

// Sum the CHUNKS partials per node, apply mask * DSIGMA_DT / max(cnt,1).
__global__ void finalize_kernel(const float* __restrict__ x,
                                const float4* __restrict__ partials,
                                float* __restrict__ out) {
    int i = blockIdx.x * blockDim.x + threadIdx.x;
    if (i >= N_NODES) return;
    int p = i >> S_LOG2;
    int s = i & (S - 1);
    float ax = 0.f, ay = 0.f, az = 0.f, aw = 0.f;
#pragma unroll
    for (int c = 0; c < CHUNKS; ++c) {
        float4 t = partials[(((size_t)(p * CHUNKS + c)) << S_LOG2) + s];
        ax += t.x; ay += t.y; az += t.z; aw += t.w;
    }
    float phi = x[i * 9 + 8];
    float cn = aw > 1.0f ? aw : 1.0f;
    float m = (fabsf(phi) < PHI_THRESH) ? (DSIGMA_DT / cn) : 0.0f;
    out[3 * i]     = m * ax;
    out[3 * i + 1] = m * ay;
    out[3 * i + 2] = m * az;
}

// ---------- fallback path (ws too small): R0-style global atomics ----------
__global__ void edge_scatter_atomic_kernel(const int* __restrict__ ei,
                                           const float* __restrict__ Tc,
                                           const float* __restrict__ pos,
                                           float4* __restrict__ accum) {
    int e = blockIdx.x * blockDim.x + threadIdx.x;
    if (e >= N_EDGES) return;
    int s = ei[e];
    int d = ei[N_EDGES + e];
    float dT = Tc[s] - Tc[d];
    float px = pos[3 * s]     - pos[3 * d];
    float py = pos[3 * s + 1] - pos[3 * d + 1];
    float pz = pos[3 * s + 2] - pos[3 * d + 2];
    float dist2 = px * px + py * py + pz * pz + EPS;
    float w = dT / dist2;
    float* a = (float*)&accum[d];
    atomicAdd(a,     w * px);
    atomicAdd(a + 1, w * py);
    atomicAdd(a + 2, w * pz);
    atomicAdd(a + 3, 1.0f);
}

__global__ void finalize_accum_kernel(const float* __restrict__ x,
                                      const float4* __restrict__ accum,
                                      float* __restrict__ out) {
    int i = blockIdx.x * blockDim.x + threadIdx.x;
    if (i >= N_NODES) return;
    float4 a = accum[i];
    float phi = x[i * 9 + 8];
    float cn = a.w > 1.0f ? a.w : 1.0f;
    float m = (fabsf(phi) < PHI_THRESH) ? (DSIGMA_DT / cn) : 0.0f;
    out[3 * i]     = m * a.x;
    out[3 * i + 1] = m * a.y;
    out[3 * i + 2] = m * a.z;
}

extern "C" void kernel_launch(void* const* d_in, const int* in_sizes, int n_in,
                              void* d_out, int out_size, void* d_ws, size_t ws_size,
                              hipStream_t stream) {
    const float* x   = (const float*)d_in[0];
    const float* pos = (const float*)d_in[1];
    const int*   ei  = (const int*)d_in[2];
    float* out = (float*)d_out;

    // ws layout: [Tc: N_NODES floats][partials: NPART*CHUNKS*S float4]
    float*  Tc       = (float*)d_ws;
    float4* partials = (float4*)((char*)d_ws + (size_t)N_NODES * sizeof(float));
    size_t need = (size_t)N_NODES * sizeof(float)
                + (size_t)NPART * CHUNKS * S * sizeof(float4);

    const int B = 256;
    extract_T_kernel<<<(N_NODES + B - 1) / B, B, 0, stream>>>(x, Tc);

    if (ws_size >= need) {
        dim3 grid(CHUNKS, NPART);
        mp_scatter_kernel<<<grid, B, 0, stream>>>((const int4*)ei, Tc, pos, partials);
        finalize_kernel<<<(N_NODES + B - 1) / B, B, 0, stream>>>(x, partials, out);
    } else {
        float4* accum = partials;  // only 1.6 MB needed
        hipMemsetAsync(accum, 0, (size_t)N_NODES * sizeof(float4), stream);
        edge_scatter_atomic_kernel<<<(N_EDGES + B - 1) / B, B, 0, stream>>>(ei, Tc, pos, accum);
        finalize_accum_kernel<<<(N_NODES + B - 1) / B, B, 0, stream>>>(x, accum, out);
    }
}

// Round 4
// 228.508 us; speedup vs baseline: 3.1276x; 1.6497x over previous
//
#include <hip/hip_runtime.h>

#define N_NODES 100000
#define N_EDGES 3200000
#define NVEC    (N_EDGES / 4)           // 800000 int4 vectors per stream

#define S_LOG2  12
#define S       (1 << S_LOG2)           // 4096 nodes per partition
#define NPART   ((N_NODES + S - 1) / S) // 25 partitions
#define CHUNKS  16
#define VPC     (NVEC / CHUNKS)         // 50000 int4 per chunk
#define QW      512                     // per-wave queue entries

constexpr float DSIGMA_DT  = -0.0001f;
constexpr float PHI_THRESH = 0.3f;
constexpr float EPS        = 1e-8f;

// posT[i] = (pos.x, pos.y, pos.z, T) — one 16B gather per endpoint.
__global__ void prep_kernel(const float* __restrict__ x,
                            const float* __restrict__ pos,
                            float4* __restrict__ posT) {
    int i = blockIdx.x * blockDim.x + threadIdx.x;
    if (i < N_NODES)
        posT[i] = make_float4(pos[3 * i], pos[3 * i + 1], pos[3 * i + 2],
                              x[9 * i + 3]);
}

// Block (c,p): scan edge chunk c with dense lanes; ballot-compact in-range
// edges into a per-wave LDS queue; drain queue with ~full lanes into SoA
// LDS accumulators; flush partials with plain coalesced stores.
__global__ __launch_bounds__(256) void mp_scatter_kernel(
        const int4* __restrict__ ei4,
        const float4* __restrict__ posT,
        float4* __restrict__ partials) {
    __shared__ float accx[S], accy[S], accz[S], accw[S];  // 64 KB SoA
    __shared__ int   queue[4 * QW];                        // 8 KB, per-wave segments

    const int c    = blockIdx.x;
    const int p    = blockIdx.y;
    const int lo   = p << S_LOG2;
    const int tid  = threadIdx.x;
    const int lane = tid & 63;
    const int wid  = tid >> 6;
    int* const q   = queue + wid * QW;

    for (int i = tid; i < S; i += 256) {
        accx[i] = 0.f; accy[i] = 0.f; accz[i] = 0.f; accw[i] = 0.f;
    }
    __syncthreads();

    const int4* __restrict__ src4 = ei4;
    const int4* __restrict__ dst4 = ei4 + NVEC;

    const int vbase = c * VPC;
    const int vend  = vbase + VPC;
    const int niter = (VPC + 255) / 256;   // uniform trip count (tail masked)

    int qcnt = 0;  // wave-uniform (every lane executes every update)

    auto drain = [&]() {
        for (int i = lane; i < qcnt; i += 64) {
            int pk = q[i];
            int s_ = pk >> S_LOG2;
            int r_ = pk & (S - 1);
            float4 a = posT[s_];
            float4 b = posT[lo + r_];
            float px = a.x - b.x, py = a.y - b.y, pz = a.z - b.z;
            float dT = a.w - b.w;
            float w  = dT / (px * px + py * py + pz * pz + EPS);
            atomicAdd(&accx[r_], w * px);
            atomicAdd(&accy[r_], w * py);
            atomicAdd(&accz[r_], w * pz);
            atomicAdd(&accw[r_], 1.0f);
        }
        qcnt = 0;
    };

    for (int it = 0; it < niter; ++it) {
        int v = vbase + it * 256 + tid;
        bool valid = v < vend;
        int4 d = valid ? dst4[v] : make_int4(-1, -1, -1, -1);
        int4 s = valid ? src4[v] : make_int4(0, 0, 0, 0);
#pragma unroll
        for (int k = 0; k < 4; ++k) {
            int dk = k == 0 ? d.x : k == 1 ? d.y : k == 2 ? d.z : d.w;
            int sk = k == 0 ? s.x : k == 1 ? s.y : k == 2 ? s.z : s.w;
            unsigned r = (unsigned)(dk - lo);
            bool pred = (r < S);
            unsigned long long m = __ballot(pred);
            int rank = __popcll(m & ((1ull << lane) - 1ull));
            if (pred) q[qcnt + rank] = (sk << S_LOG2) | (int)r;
            qcnt += (int)__popcll(m);
        }
        if (qcnt >= QW - 256) drain();
    }
    drain();
    __syncthreads();

    float4* __restrict__ outp = partials + ((size_t)(p * CHUNKS + c) << S_LOG2);
    for (int i = tid; i < S; i += 256)
        outp[i] = make_float4(accx[i], accy[i], accz[i], accw[i]);
}

// Sum the CHUNKS partials per node, apply mask * DSIGMA_DT / max(cnt,1).
__global__ void finalize_kernel(const float* __restrict__ x,
                                const float4* __restrict__ partials,
                                float* __restrict__ out) {
    int i = blockIdx.x * blockDim.x + threadIdx.x;
    if (i >= N_NODES) return;
    int p = i >> S_LOG2;
    int s = i & (S - 1);
    float ax = 0.f, ay = 0.f, az = 0.f, aw = 0.f;
#pragma unroll
    for (int c = 0; c < CHUNKS; ++c) {
        float4 t = partials[(((size_t)(p * CHUNKS + c)) << S_LOG2) + s];
        ax += t.x; ay += t.y; az += t.z; aw += t.w;
    }
    float phi = x[i * 9 + 8];
    float cn = aw > 1.0f ? aw : 1.0f;
    float m = (fabsf(phi) < PHI_THRESH) ? (DSIGMA_DT / cn) : 0.0f;
    out[3 * i]     = m * ax;
    out[3 * i + 1] = m * ay;
    out[3 * i + 2] = m * az;
}

// ---------- fallback path (ws too small): global atomics ----------
__global__ void edge_scatter_atomic_kernel(const int* __restrict__ ei,
                                           const float4* __restrict__ posT,
                                           float4* __restrict__ accum) {
    int e = blockIdx.x * blockDim.x + threadIdx.x;
    if (e >= N_EDGES) return;
    int s = ei[e];
    int d = ei[N_EDGES + e];
    float4 a = posT[s];
    float4 b = posT[d];
    float px = a.x - b.x, py = a.y - b.y, pz = a.z - b.z;
    float dT = a.w - b.w;
    float w  = dT / (px * px + py * py + pz * pz + EPS);
    float* ac = (float*)&accum[d];
    atomicAdd(ac,     w * px);
    atomicAdd(ac + 1, w * py);
    atomicAdd(ac + 2, w * pz);
    atomicAdd(ac + 3, 1.0f);
}

__global__ void finalize_accum_kernel(const float* __restrict__ x,
                                      const float4* __restrict__ accum,
                                      float* __restrict__ out) {
    int i = blockIdx.x * blockDim.x + threadIdx.x;
    if (i >= N_NODES) return;
    float4 a = accum[i];
    float phi = x[i * 9 + 8];
    float cn = a.w > 1.0f ? a.w : 1.0f;
    float m = (fabsf(phi) < PHI_THRESH) ? (DSIGMA_DT / cn) : 0.0f;
    out[3 * i]     = m * a.x;
    out[3 * i + 1] = m * a.y;
    out[3 * i + 2] = m * a.z;
}

extern "C" void kernel_launch(void* const* d_in, const int* in_sizes, int n_in,
                              void* d_out, int out_size, void* d_ws, size_t ws_size,
                              hipStream_t stream) {
    const float* x   = (const float*)d_in[0];
    const float* pos = (const float*)d_in[1];
    const int*   ei  = (const int*)d_in[2];
    float* out = (float*)d_out;

    // ws layout: [posT: N_NODES float4][partials: NPART*CHUNKS*S float4]
    float4* posT     = (float4*)d_ws;
    float4* partials = (float4*)((char*)d_ws + (size_t)N_NODES * sizeof(float4));
    size_t need = (size_t)N_NODES * sizeof(float4)
                + (size_t)NPART * CHUNKS * S * sizeof(float4);

    const int B = 256;
    prep_kernel<<<(N_NODES + B - 1) / B, B, 0, stream>>>(x, pos, posT);

    if (ws_size >= need) {
        dim3 grid(CHUNKS, NPART);
        mp_scatter_kernel<<<grid, B, 0, stream>>>((const int4*)ei, posT, partials);
        finalize_kernel<<<(N_NODES + B - 1) / B, B, 0, stream>>>(x, partials, out);
    } else {
        float4* accum = partials;  // 1.6 MB
        hipMemsetAsync(accum, 0, (size_t)N_NODES * sizeof(float4), stream);
        edge_scatter_atomic_kernel<<<(N_EDGES + B - 1) / B, B, 0, stream>>>(ei, posT, accum);
        finalize_accum_kernel<<<(N_NODES + B - 1) / B, B, 0, stream>>>(x, accum, out);
    }
}

// Round 5
// 185.007 us; speedup vs baseline: 3.8630x; 1.2351x over previous
//
#include <hip/hip_runtime.h>

#define N_NODES 100000
#define N_EDGES 3200000
#define NVEC    (N_EDGES / 4)           // 800000 int4 per stream

#define S_LOG2  12
#define S       (1 << S_LOG2)           // 4096 nodes per partition
#define NPART   ((N_NODES + S - 1) / S) // 25 partitions
#define NC      16                      // chunks per partition (pass B / scan path)
#define QW      512                     // scan-path per-wave queue entries

#define EPB     8192                    // edges per pass-A block
#define NB      ((N_EDGES + EPB - 1) / EPB)   // 391
#define CAP     140000                  // bucket capacity (mean 131072, sigma ~354)

constexpr float DSIGMA_DT  = -0.0001f;
constexpr float PHI_THRESH = 0.3f;
constexpr float EPS        = 1e-8f;

// posT[i] = (pos.x, pos.y, pos.z, T) — one 16B gather per endpoint.
__global__ void prep_kernel(const float* __restrict__ x,
                            const float* __restrict__ pos,
                            float4* __restrict__ posT) {
    int i = blockIdx.x * blockDim.x + threadIdx.x;
    if (i < N_NODES)
        posT[i] = make_float4(pos[3 * i], pos[3 * i + 1], pos[3 * i + 2],
                              x[9 * i + 3]);
}

// ---------------- Pass A: counting-sort edges into 25 partition buckets ----
__global__ __launch_bounds__(512) void bin_kernel(const int4* __restrict__ ei4,
                                                  int* __restrict__ gcur,
                                                  int* __restrict__ buckets) {
    __shared__ int lbuf[EPB];                 // 32 KB locally sorted entries
    __shared__ int hist[NPART], lofs[NPART], cur[NPART], baseg[NPART];
    const int tid = threadIdx.x;
    const int ebase = blockIdx.x * EPB;
    const int n = min(EPB, N_EDGES - ebase);  // multiple of 4
    const int nv = n >> 2;
    const int4* __restrict__ src4 = ei4 + (ebase >> 2);
    const int4* __restrict__ dst4 = ei4 + NVEC + (ebase >> 2);

    if (tid < NPART) hist[tid] = 0;
    __syncthreads();

    for (int v = tid; v < nv; v += 512) {
        int4 d = dst4[v];
        atomicAdd(&hist[d.x >> S_LOG2], 1);
        atomicAdd(&hist[d.y >> S_LOG2], 1);
        atomicAdd(&hist[d.z >> S_LOG2], 1);
        atomicAdd(&hist[d.w >> S_LOG2], 1);
    }
    __syncthreads();

    if (tid == 0) {
        int run = 0;
        for (int b = 0; b < NPART; ++b) { lofs[b] = run; cur[b] = run; run += hist[b]; }
    }
    if (tid < NPART) baseg[tid] = atomicAdd(&gcur[tid], hist[tid]);
    __syncthreads();

    for (int v = tid; v < nv; v += 512) {
        int4 s = src4[v];
        int4 d = dst4[v];
#pragma unroll
        for (int k = 0; k < 4; ++k) {
            int dk = k == 0 ? d.x : k == 1 ? d.y : k == 2 ? d.z : d.w;
            int sk = k == 0 ? s.x : k == 1 ? s.y : k == 2 ? s.z : s.w;
            int bin = dk >> S_LOG2;
            int pk  = (sk << S_LOG2) | (dk & (S - 1));
            int off = atomicAdd(&cur[bin], 1);
            lbuf[off] = pk;
        }
    }
    __syncthreads();

    // coalesced per-bin copy-out to reserved global runs
    for (int b = 0; b < NPART; ++b) {
        int cnt = hist[b], lb = lofs[b], gb = baseg[b];
        int* __restrict__ dp = buckets + (size_t)b * CAP + gb;
        for (int i = tid; i < cnt; i += 512)
            if (gb + i < CAP) dp[i] = lbuf[lb + i];
    }
}

// ---------------- Pass B: dense per-partition accumulation ----------------
__global__ __launch_bounds__(512) void part_kernel(const int* __restrict__ gcur,
                                                   const int* __restrict__ buckets,
                                                   const float4* __restrict__ posT,
                                                   float4* __restrict__ partials) {
    __shared__ float accx[S], accy[S], accz[S], accw[S];  // 64 KB SoA
    const int c = blockIdx.x, p = blockIdx.y, tid = threadIdx.x;
    const int lo = p << S_LOG2;

    for (int i = tid; i < S; i += 512) {
        accx[i] = 0.f; accy[i] = 0.f; accz[i] = 0.f; accw[i] = 0.f;
    }
    __syncthreads();

    const int len = min(gcur[p], CAP);
    const int beg = (int)((long long)len * c / NC);
    const int end = (int)((long long)len * (c + 1) / NC);
    const int* __restrict__ bp = buckets + (size_t)p * CAP;

    for (int i = beg + tid; i < end; i += 512) {
        int pk = bp[i];
        int s_ = pk >> S_LOG2;
        int r_ = pk & (S - 1);
        float4 a = posT[s_];
        float4 b = posT[lo + r_];
        float px = a.x - b.x, py = a.y - b.y, pz = a.z - b.z;
        float dT = a.w - b.w;
        float w  = dT / (px * px + py * py + pz * pz + EPS);
        atomicAdd(&accx[r_], w * px);
        atomicAdd(&accy[r_], w * py);
        atomicAdd(&accz[r_], w * pz);
        atomicAdd(&accw[r_], 1.0f);
    }
    __syncthreads();

    float4* __restrict__ outp = partials + ((size_t)(p * NC + c) << S_LOG2);
    for (int i = tid; i < S; i += 512)
        outp[i] = make_float4(accx[i], accy[i], accz[i], accw[i]);
}

// Sum the NC partials per node, apply mask * DSIGMA_DT / max(cnt,1).
__global__ void finalize_kernel(const float* __restrict__ x,
                                const float4* __restrict__ partials,
                                float* __restrict__ out) {
    int i = blockIdx.x * blockDim.x + threadIdx.x;
    if (i >= N_NODES) return;
    int p = i >> S_LOG2;
    int s = i & (S - 1);
    float ax = 0.f, ay = 0.f, az = 0.f, aw = 0.f;
#pragma unroll
    for (int c = 0; c < NC; ++c) {
        float4 t = partials[(((size_t)(p * NC + c)) << S_LOG2) + s];
        ax += t.x; ay += t.y; az += t.z; aw += t.w;
    }
    float phi = x[i * 9 + 8];
    float cn = aw > 1.0f ? aw : 1.0f;
    float m = (fabsf(phi) < PHI_THRESH) ? (DSIGMA_DT / cn) : 0.0f;
    out[3 * i]     = m * ax;
    out[3 * i + 1] = m * ay;
    out[3 * i + 2] = m * az;
}

// ---------------- mid fallback: R3 scan+queue path (ws >= 27.8 MB) --------
__global__ __launch_bounds__(256) void mp_scatter_kernel(
        const int4* __restrict__ ei4,
        const float4* __restrict__ posT,
        float4* __restrict__ partials) {
    __shared__ float accx[S], accy[S], accz[S], accw[S];
    __shared__ int   queue[4 * QW];

    const int c    = blockIdx.x;
    const int p    = blockIdx.y;
    const int lo   = p << S_LOG2;
    const int tid  = threadIdx.x;
    const int lane = tid & 63;
    const int wid  = tid >> 6;
    int* const q   = queue + wid * QW;

    for (int i = tid; i < S; i += 256) {
        accx[i] = 0.f; accy[i] = 0.f; accz[i] = 0.f; accw[i] = 0.f;
    }
    __syncthreads();

    const int4* __restrict__ src4 = ei4;
    const int4* __restrict__ dst4 = ei4 + NVEC;
    const int VPC = NVEC / NC;
    const int vbase = c * VPC;
    const int vend  = vbase + VPC;
    const int niter = (VPC + 255) / 256;
    int qcnt = 0;

    auto drain = [&]() {
        for (int i = lane; i < qcnt; i += 64) {
            int pk = q[i];
            int s_ = pk >> S_LOG2;
            int r_ = pk & (S - 1);
            float4 a = posT[s_];
            float4 b = posT[lo + r_];
            float px = a.x - b.x, py = a.y - b.y, pz = a.z - b.z;
            float dT = a.w - b.w;
            float w  = dT / (px * px + py * py + pz * pz + EPS);
            atomicAdd(&accx[r_], w * px);
            atomicAdd(&accy[r_], w * py);
            atomicAdd(&accz[r_], w * pz);
            atomicAdd(&accw[r_], 1.0f);
        }
        qcnt = 0;
    };

    for (int it = 0; it < niter; ++it) {
        int v = vbase + it * 256 + tid;
        bool valid = v < vend;
        int4 d = valid ? dst4[v] : make_int4(-1, -1, -1, -1);
        int4 s = valid ? src4[v] : make_int4(0, 0, 0, 0);
#pragma unroll
        for (int k = 0; k < 4; ++k) {
            int dk = k == 0 ? d.x : k == 1 ? d.y : k == 2 ? d.z : d.w;
            int sk = k == 0 ? s.x : k == 1 ? s.y : k == 2 ? s.z : s.w;
            unsigned r = (unsigned)(dk - lo);
            bool pred = (r < S);
            unsigned long long m = __ballot(pred);
            int rank = __popcll(m & ((1ull << lane) - 1ull));
            if (pred) q[qcnt + rank] = (sk << S_LOG2) | (int)r;
            qcnt += (int)__popcll(m);
        }
        if (qcnt >= QW - 256) drain();
    }
    drain();
    __syncthreads();

    float4* __restrict__ outp = partials + ((size_t)(p * NC + c) << S_LOG2);
    for (int i = tid; i < S; i += 256)
        outp[i] = make_float4(accx[i], accy[i], accz[i], accw[i]);
}

// ---------------- last fallback: global atomics ---------------------------
__global__ void edge_scatter_atomic_kernel(const int* __restrict__ ei,
                                           const float4* __restrict__ posT,
                                           float4* __restrict__ accum) {
    int e = blockIdx.x * blockDim.x + threadIdx.x;
    if (e >= N_EDGES) return;
    int s = ei[e];
    int d = ei[N_EDGES + e];
    float4 a = posT[s];
    float4 b = posT[d];
    float px = a.x - b.x, py = a.y - b.y, pz = a.z - b.z;
    float dT = a.w - b.w;
    float w  = dT / (px * px + py * py + pz * pz + EPS);
    float* ac = (float*)&accum[d];
    atomicAdd(ac,     w * px);
    atomicAdd(ac + 1, w * py);
    atomicAdd(ac + 2, w * pz);
    atomicAdd(ac + 3, 1.0f);
}

__global__ void finalize_accum_kernel(const float* __restrict__ x,
                                      const float4* __restrict__ accum,
                                      float* __restrict__ out) {
    int i = blockIdx.x * blockDim.x + threadIdx.x;
    if (i >= N_NODES) return;
    float4 a = accum[i];
    float phi = x[i * 9 + 8];
    float cn = a.w > 1.0f ? a.w : 1.0f;
    float m = (fabsf(phi) < PHI_THRESH) ? (DSIGMA_DT / cn) : 0.0f;
    out[3 * i]     = m * a.x;
    out[3 * i + 1] = m * a.y;
    out[3 * i + 2] = m * a.z;
}

extern "C" void kernel_launch(void* const* d_in, const int* in_sizes, int n_in,
                              void* d_out, int out_size, void* d_ws, size_t ws_size,
                              hipStream_t stream) {
    const float* x   = (const float*)d_in[0];
    const float* pos = (const float*)d_in[1];
    const int*   ei  = (const int*)d_in[2];
    float* out = (float*)d_out;

    // ws layout: [posT][partials][gcur pad 128B][buckets]
    const size_t posT_b = (size_t)N_NODES * sizeof(float4);          // 1.6 MB
    const size_t part_b = (size_t)NC * NPART * S * sizeof(float4);   // 26.2 MB
    const size_t gcur_b = 128;
    const size_t buck_b = (size_t)NPART * CAP * sizeof(int);         // 14.0 MB

    char* w = (char*)d_ws;
    float4* posT     = (float4*)w;
    float4* partials = (float4*)(w + posT_b);
    int*    gcur     = (int*)(w + posT_b + part_b);
    int*    buckets  = (int*)(w + posT_b + part_b + gcur_b);

    const size_t need_full = posT_b + part_b + gcur_b + buck_b;
    const size_t need_scan = posT_b + part_b;

    const int B = 256;
    prep_kernel<<<(N_NODES + B - 1) / B, B, 0, stream>>>(x, pos, posT);

    if (ws_size >= need_full) {
        hipMemsetAsync(gcur, 0, gcur_b, stream);
        bin_kernel<<<NB, 512, 0, stream>>>((const int4*)ei, gcur, buckets);
        dim3 grid(NC, NPART);
        part_kernel<<<grid, 512, 0, stream>>>(gcur, buckets, posT, partials);
        finalize_kernel<<<(N_NODES + B - 1) / B, B, 0, stream>>>(x, partials, out);
    } else if (ws_size >= need_scan) {
        dim3 grid(NC, NPART);
        mp_scatter_kernel<<<grid, B, 0, stream>>>((const int4*)ei, posT, partials);
        finalize_kernel<<<(N_NODES + B - 1) / B, B, 0, stream>>>(x, partials, out);
    } else {
        float4* accum = partials;  // 1.6 MB
        hipMemsetAsync(accum, 0, (size_t)N_NODES * sizeof(float4), stream);
        edge_scatter_atomic_kernel<<<(N_EDGES + B - 1) / B, B, 0, stream>>>(ei, posT, accum);
        finalize_accum_kernel<<<(N_NODES + B - 1) / B, B, 0, stream>>>(x, accum, out);
    }
}